// Round 1
// baseline (1058.245 us; speedup 1.0000x reference)
//
#include <hip/hip_runtime.h>
#include <hip/hip_bf16.h>

#define ALPHA 0.2f

// ---------------------------------------------------------------------------
// mm: C[M, ldc] (+ col offset 128*blockIdx.y) = A[M,128] @ B_k[128,128]
// B_k = B + blockIdx.y*128*128 (row-major [in][out]).
// Tile: 32 rows/block, BK=64 chunks. LDS = 32KB (Bs) + 8KB (As) = 40KB.
// Thread t: col = t&127, rows rbase..rbase+15 (rbase = (t>>7)*16).
// ---------------------------------------------------------------------------
__global__ __launch_bounds__(256) void mm_kernel(const float* __restrict__ A,
                                                 const float* __restrict__ B,
                                                 float* __restrict__ C,
                                                 int M, int ldc) {
    __shared__ float Bs[64 * 128];   // [ci][col]
    __shared__ float As[32 * 64];    // [r][ci]
    const int tid  = threadIdx.x;
    const int row0 = blockIdx.x * 32;
    const int kblk = blockIdx.y;           // which 128x128 slice of B
    const float* Bk = B + (size_t)kblk * 128 * 128;
    const int coff = kblk * 128;

    const int col   = tid & 127;
    const int rbase = (tid >> 7) * 16;

    float acc[16];
#pragma unroll
    for (int j = 0; j < 16; ++j) acc[j] = 0.f;

    for (int kb = 0; kb < 128; kb += 64) {
        // load Bs: 64x128 floats = 2048 float4, 8 per thread
        {
            const float4* B4  = (const float4*)Bk;
            float4*       Bs4 = (float4*)Bs;
            for (int i = tid; i < 2048; i += 256) {
                int ci = i >> 5, c4 = i & 31;
                Bs4[i] = B4[(size_t)(kb + ci) * 32 + c4];
            }
        }
        // load As: 32x64 floats = 512 float4, 2 per thread (guard rows)
        {
            float4* As4 = (float4*)As;
            for (int i = tid; i < 512; i += 256) {
                int r = i >> 4, k4 = i & 15;
                int rg = row0 + r;
                float4 v = make_float4(0.f, 0.f, 0.f, 0.f);
                if (rg < M) v = ((const float4*)A)[(size_t)rg * 32 + (kb >> 2) + k4];
                As4[i] = v;
            }
        }
        __syncthreads();
#pragma unroll 4
        for (int ci = 0; ci < 64; ++ci) {
            float b = Bs[ci * 128 + col];
#pragma unroll
            for (int j = 0; j < 16; ++j)
                acc[j] += As[(rbase + j) * 64 + ci] * b;  // As read is wave-uniform -> broadcast
        }
        __syncthreads();
    }
#pragma unroll
    for (int j = 0; j < 16; ++j) {
        int rg = row0 + rbase + j;
        if (rg < M) C[(size_t)rg * ldc + coff + col] = acc[j];
    }
}

// ---------------------------------------------------------------------------
// scores: one wave per node, s1[n]=dot(Wh[n],a1), s2[n]=dot(Wh[n],a2)
// ---------------------------------------------------------------------------
__global__ __launch_bounds__(256) void scores_kernel(const float* __restrict__ Wh,
                                                     const float* __restrict__ a1,
                                                     const float* __restrict__ a2,
                                                     float* __restrict__ s1,
                                                     float* __restrict__ s2, int N) {
    int wid  = (blockIdx.x * blockDim.x + threadIdx.x) >> 6;
    int lane = threadIdx.x & 63;
    if (wid >= N) return;
    const float* row = Wh + (size_t)wid * 128;
    float v0 = row[lane], v1 = row[64 + lane];
    float x1 = v0 * a1[lane] + v1 * a1[64 + lane];
    float x2 = v0 * a2[lane] + v1 * a2[64 + lane];
#pragma unroll
    for (int off = 32; off > 0; off >>= 1) {
        x1 += __shfl_down(x1, off);
        x2 += __shfl_down(x2, off);
    }
    if (lane == 0) { s1[wid] = x1; s2[wid] = x2; }
}

// ---------------------------------------------------------------------------
// edge1: thread per edge. ex = exp(leakyrelu(s1[src]+s2[dst]) * ef[k]);
// store ex, atomicAdd into denom[dst][k]. (max-shift skipped: shift-invariant,
// scores bounded ~|11| so no fp32 overflow; epsilon negligible.)
// ---------------------------------------------------------------------------
__global__ __launch_bounds__(256) void edge1_kernel(const int* __restrict__ ei,
                                                    const float* __restrict__ ef,
                                                    const float* __restrict__ s1,
                                                    const float* __restrict__ s2,
                                                    float* __restrict__ exbuf,
                                                    float* __restrict__ denom, int E) {
    int e = blockIdx.x * blockDim.x + threadIdx.x;
    if (e >= E) return;
    int src = ei[e];
    int dst = ei[E + e];
    float s = s1[src] + s2[dst];
    s = (s >= 0.f) ? s : ALPHA * s;
#pragma unroll
    for (int k = 0; k < 3; ++k) {
        float ex = __expf(s * ef[e * 3 + k]);
        exbuf[e * 3 + k] = ex;
        atomicAdd(denom + (size_t)dst * 3 + k, ex);
    }
}

// ---------------------------------------------------------------------------
// edge2: one wave per edge. att_k = ex_k/(denom[dst][k]+1e-16);
// out[dst][c] += sum_k att_k * Y[src][k][c]   (lane handles 2 channels)
// ---------------------------------------------------------------------------
__global__ __launch_bounds__(256) void edge2_kernel(const int* __restrict__ ei,
                                                    const float* __restrict__ exbuf,
                                                    const float* __restrict__ denom,
                                                    const float* __restrict__ Y,
                                                    float* __restrict__ out, int E) {
    int w    = (blockIdx.x * blockDim.x + threadIdx.x) >> 6;
    int lane = threadIdx.x & 63;
    if (w >= E) return;
    int src = ei[w];
    int dst = ei[E + w];
    float at0 = exbuf[w * 3 + 0] / (denom[(size_t)dst * 3 + 0] + 1e-16f);
    float at1 = exbuf[w * 3 + 1] / (denom[(size_t)dst * 3 + 1] + 1e-16f);
    float at2 = exbuf[w * 3 + 2] / (denom[(size_t)dst * 3 + 2] + 1e-16f);
    const float2* Yr = (const float2*)(Y + (size_t)src * 384);
    float2 y0 = Yr[lane];
    float2 y1 = Yr[64 + lane];
    float2 y2 = Yr[128 + lane];
    float m0 = at0 * y0.x + at1 * y1.x + at2 * y2.x;
    float m1 = at0 * y0.y + at1 * y1.y + at2 * y2.y;
    float* op = out + (size_t)dst * 128 + lane * 2;
    atomicAdd(op, m0);
    atomicAdd(op + 1, m1);
}

// ---------------------------------------------------------------------------
extern "C" void kernel_launch(void* const* d_in, const int* in_sizes, int n_in,
                              void* d_out, int out_size, void* d_ws, size_t ws_size,
                              hipStream_t stream) {
    const float* h    = (const float*)d_in[0];
    const int*   ei   = (const int*)d_in[1];    // [2, E]
    const float* ef   = (const float*)d_in[2];  // [E, 3]
    const float* W    = (const float*)d_in[3];  // [128,128]
    const float* a1   = (const float*)d_in[4];  // [128]
    const float* a2   = (const float*)d_in[5];  // [128]
    const float* Wout = (const float*)d_in[6];  // [384,128]
    float*       out  = (float*)d_out;

    const int N = in_sizes[0] / 128;  // 50000
    const int E = in_sizes[2] / 3;    // 800000

    // workspace layout (floats)
    float* ws    = (float*)d_ws;
    float* Wh    = ws;                          // N*128
    float* Y     = Wh + (size_t)N * 128;        // N*384  (layout [n][k][c])
    float* s1    = Y + (size_t)N * 384;         // N
    float* s2    = s1 + N;                      // N
    float* exbuf = s2 + N;                      // E*3
    float* denom = exbuf + (size_t)E * 3;       // N*3

    hipMemsetAsync(out, 0, (size_t)N * 128 * sizeof(float), stream);
    hipMemsetAsync(denom, 0, (size_t)N * 3 * sizeof(float), stream);

    const int mblocks = (N + 31) / 32;
    // Wh = h @ W
    mm_kernel<<<dim3(mblocks, 1), 256, 0, stream>>>(h, W, Wh, N, 128);
    // Y[:, k*128:(k+1)*128] = Wh @ Wout_k  for k=0..2
    mm_kernel<<<dim3(mblocks, 3), 256, 0, stream>>>(Wh, Wout, Y, N, 384);
    // s1, s2
    scores_kernel<<<(N * 64 + 255) / 256, 256, 0, stream>>>(Wh, a1, a2, s1, s2, N);
    // edge softmax numerators + denominators
    edge1_kernel<<<(E + 255) / 256, 256, 0, stream>>>(ei, ef, s1, s2, exbuf, denom, E);
    // weighted gather + scatter-add
    long long tthreads = (long long)E * 64;
    edge2_kernel<<<(int)((tthreads + 255) / 256), 256, 0, stream>>>(ei, exbuf, denom, Y, out, E);
}

// Round 2
// 651.839 us; speedup vs baseline: 1.6235x; 1.6235x over previous
//
#include <hip/hip_runtime.h>
#include <hip/hip_bf16.h>

#define ALPHA 0.2f

// ---------------------------------------------------------------------------
// mm: C[M, ldc] (+ col offset 128*blockIdx.y) = A[M,128] @ B_k[128,128]
// (unchanged from R1 — revisit after edge phase is fixed)
// ---------------------------------------------------------------------------
__global__ __launch_bounds__(256) void mm_kernel(const float* __restrict__ A,
                                                 const float* __restrict__ B,
                                                 float* __restrict__ C,
                                                 int M, int ldc) {
    __shared__ float Bs[64 * 128];   // [ci][col]
    __shared__ float As[32 * 64];    // [r][ci]
    const int tid  = threadIdx.x;
    const int row0 = blockIdx.x * 32;
    const int kblk = blockIdx.y;
    const float* Bk = B + (size_t)kblk * 128 * 128;
    const int coff = kblk * 128;

    const int col   = tid & 127;
    const int rbase = (tid >> 7) * 16;

    float acc[16];
#pragma unroll
    for (int j = 0; j < 16; ++j) acc[j] = 0.f;

    for (int kb = 0; kb < 128; kb += 64) {
        {
            const float4* B4  = (const float4*)Bk;
            float4*       Bs4 = (float4*)Bs;
            for (int i = tid; i < 2048; i += 256) {
                int ci = i >> 5, c4 = i & 31;
                Bs4[i] = B4[(size_t)(kb + ci) * 32 + c4];
            }
        }
        {
            float4* As4 = (float4*)As;
            for (int i = tid; i < 512; i += 256) {
                int r = i >> 4, k4 = i & 15;
                int rg = row0 + r;
                float4 v = make_float4(0.f, 0.f, 0.f, 0.f);
                if (rg < M) v = ((const float4*)A)[(size_t)rg * 32 + (kb >> 2) + k4];
                As4[i] = v;
            }
        }
        __syncthreads();
#pragma unroll 4
        for (int ci = 0; ci < 64; ++ci) {
            float b = Bs[ci * 128 + col];
#pragma unroll
            for (int j = 0; j < 16; ++j)
                acc[j] += As[(rbase + j) * 64 + ci] * b;
        }
        __syncthreads();
    }
#pragma unroll
    for (int j = 0; j < 16; ++j) {
        int rg = row0 + rbase + j;
        if (rg < M) C[(size_t)rg * ldc + coff + col] = acc[j];
    }
}

// ---------------------------------------------------------------------------
// scores: one wave per node, s1[n]=dot(Wh[n],a1), s2[n]=dot(Wh[n],a2)
// ---------------------------------------------------------------------------
__global__ __launch_bounds__(256) void scores_kernel(const float* __restrict__ Wh,
                                                     const float* __restrict__ a1,
                                                     const float* __restrict__ a2,
                                                     float* __restrict__ s1,
                                                     float* __restrict__ s2, int N) {
    int wid  = (blockIdx.x * blockDim.x + threadIdx.x) >> 6;
    int lane = threadIdx.x & 63;
    if (wid >= N) return;
    const float* row = Wh + (size_t)wid * 128;
    float v0 = row[lane], v1 = row[64 + lane];
    float x1 = v0 * a1[lane] + v1 * a1[64 + lane];
    float x2 = v0 * a2[lane] + v1 * a2[64 + lane];
#pragma unroll
    for (int off = 32; off > 0; off >>= 1) {
        x1 += __shfl_down(x1, off);
        x2 += __shfl_down(x2, off);
    }
    if (lane == 0) { s1[wid] = x1; s2[wid] = x2; }
}

// ---------------------------------------------------------------------------
// hist: counts[dst]++ per edge (int atomics, TCC-side, cheap)
// ---------------------------------------------------------------------------
__global__ __launch_bounds__(256) void hist_kernel(const int* __restrict__ ei,
                                                   int* __restrict__ counts, int E) {
    int e = blockIdx.x * blockDim.x + threadIdx.x;
    if (e < E) atomicAdd(&counts[ei[E + e]], 1);
}

// ---------------------------------------------------------------------------
// scan: single-block exclusive prefix sum of counts -> rowptr[N+1], and
// initializes next[] = rowptr[0..N) as the scatter cursors.
// 256 threads, shuffle-scan per wave + LDS across 4 waves, serial chunks.
// ---------------------------------------------------------------------------
__global__ __launch_bounds__(256) void scan_kernel(const int* __restrict__ counts,
                                                   int* __restrict__ rowptr,
                                                   int* __restrict__ next, int N) {
    __shared__ int wsum[4];
    __shared__ int carry_s;
    const int tid  = threadIdx.x;
    const int lane = tid & 63;
    const int wv   = tid >> 6;
    if (tid == 0) carry_s = 0;
    __syncthreads();
    for (int base = 0; base < N; base += 256) {
        int i = base + tid;
        int v = (i < N) ? counts[i] : 0;
        int incl = v;
#pragma unroll
        for (int off = 1; off < 64; off <<= 1) {
            int t = __shfl_up(incl, off);
            if (lane >= off) incl += t;
        }
        if (lane == 63) wsum[wv] = incl;
        __syncthreads();
        int woff = 0;
        for (int w2 = 0; w2 < wv; ++w2) woff += wsum[w2];
        int total = wsum[0] + wsum[1] + wsum[2] + wsum[3];
        int excl = carry_s + woff + incl - v;
        if (i < N) { rowptr[i] = excl; next[i] = excl; }
        __syncthreads();               // all reads of carry_s done
        if (tid == 0) carry_s += total;
        __syncthreads();
    }
    if (threadIdx.x == 0) rowptr[N] = carry_s;
}

// ---------------------------------------------------------------------------
// scatter: per edge, compute ex triple (leaky_relu score * edgefeat, exp'd),
// claim a slot in dst's CSR segment, write a 16B record {ex0,ex1,ex2,src}.
// Max-shift skipped: softmax is shift-invariant; scores bounded (~|11|) so
// fp32 exp can't overflow; the 1e-16 epsilon is negligible either way.
// ---------------------------------------------------------------------------
__global__ __launch_bounds__(256) void scatter_kernel(const int* __restrict__ ei,
                                                      const float* __restrict__ ef,
                                                      const float* __restrict__ s1,
                                                      const float* __restrict__ s2,
                                                      int* __restrict__ next,
                                                      float4* __restrict__ rec, int E) {
    int e = blockIdx.x * blockDim.x + threadIdx.x;
    if (e >= E) return;
    int src = ei[e];
    int dst = ei[E + e];
    float s = s1[src] + s2[dst];
    s = (s >= 0.f) ? s : ALPHA * s;
    float ex0 = __expf(s * ef[e * 3 + 0]);
    float ex1 = __expf(s * ef[e * 3 + 1]);
    float ex2 = __expf(s * ef[e * 3 + 2]);
    int pos = atomicAdd(&next[dst], 1);
    rec[pos] = make_float4(ex0, ex1, ex2, __int_as_float(src));
}

// ---------------------------------------------------------------------------
// agg: one wave per node. Pass 1 over the node's edge records sums the
// softmax denominators (wave-uniform broadcast loads, L1-hot on pass 2).
// Pass 2 gathers Y[src] (1536B coalesced row) and accumulates att-weighted
// sum in registers (2 channels/lane). One coalesced float2 store per lane.
// No atomics anywhere.
// ---------------------------------------------------------------------------
__global__ __launch_bounds__(256) void agg_kernel(const float4* __restrict__ rec,
                                                  const int* __restrict__ rowptr,
                                                  const float* __restrict__ Y,
                                                  float* __restrict__ out, int N) {
    int node = (blockIdx.x * blockDim.x + threadIdx.x) >> 6;
    int lane = threadIdx.x & 63;
    if (node >= N) return;
    int beg = rowptr[node], end = rowptr[node + 1];

    float d0 = 0.f, d1 = 0.f, d2 = 0.f;
    for (int j = beg; j < end; ++j) {
        float4 r = rec[j];
        d0 += r.x; d1 += r.y; d2 += r.z;
    }
    float inv0 = 1.f / (d0 + 1e-16f);
    float inv1 = 1.f / (d1 + 1e-16f);
    float inv2 = 1.f / (d2 + 1e-16f);

    float a0 = 0.f, a1 = 0.f;
    for (int j = beg; j < end; ++j) {
        float4 r = rec[j];
        int src = __float_as_int(r.w);
        float w0 = r.x * inv0, w1 = r.y * inv1, w2 = r.z * inv2;
        const float2* Yr = (const float2*)(Y + (size_t)src * 384);
        float2 y0 = Yr[lane];
        float2 y1 = Yr[64 + lane];
        float2 y2 = Yr[128 + lane];
        a0 += w0 * y0.x + w1 * y1.x + w2 * y2.x;
        a1 += w0 * y0.y + w1 * y1.y + w2 * y2.y;
    }
    ((float2*)(out + (size_t)node * 128))[lane] = make_float2(a0, a1);
}

// ---------------------------------------------------------------------------
extern "C" void kernel_launch(void* const* d_in, const int* in_sizes, int n_in,
                              void* d_out, int out_size, void* d_ws, size_t ws_size,
                              hipStream_t stream) {
    const float* h    = (const float*)d_in[0];
    const int*   ei   = (const int*)d_in[1];    // [2, E]
    const float* ef   = (const float*)d_in[2];  // [E, 3]
    const float* W    = (const float*)d_in[3];  // [128,128]
    const float* a1   = (const float*)d_in[4];  // [128]
    const float* a2   = (const float*)d_in[5];  // [128]
    const float* Wout = (const float*)d_in[6];  // [384,128]
    float*       out  = (float*)d_out;

    const int N = in_sizes[0] / 128;  // 50000
    const int E = in_sizes[2] / 3;    // 800000

    // workspace layout
    float* ws   = (float*)d_ws;
    float* Wh   = ws;                           // N*128
    float* Y    = Wh + (size_t)N * 128;         // N*384  (layout [n][k][c])
    float* s1   = Y + (size_t)N * 384;          // N
    float* s2   = s1 + N;                       // N
    float4* rec = (float4*)(s2 + N);            // E float4 (16B-aligned: offset even)
    int* counts = (int*)(rec + E);              // N
    int* rowptr = counts + N;                   // N+1
    int* next   = rowptr + N + 1;               // N

    hipMemsetAsync(counts, 0, (size_t)N * sizeof(int), stream);

    const int mblocks = (N + 31) / 32;
    // Wh = h @ W
    mm_kernel<<<dim3(mblocks, 1), 256, 0, stream>>>(h, W, Wh, N, 128);
    // Y[:, k*128:(k+1)*128] = Wh @ Wout_k
    mm_kernel<<<dim3(mblocks, 3), 256, 0, stream>>>(Wh, Wout, Y, N, 384);
    // node scores
    scores_kernel<<<(N * 64 + 255) / 256, 256, 0, stream>>>(Wh, a1, a2, s1, s2, N);
    // CSR build: histogram -> scan -> scatter records
    hist_kernel<<<(E + 255) / 256, 256, 0, stream>>>(ei, counts, E);
    scan_kernel<<<1, 256, 0, stream>>>(counts, rowptr, next, N);
    scatter_kernel<<<(E + 255) / 256, 256, 0, stream>>>(ei, ef, s1, s2, next, rec, E);
    // atomic-free aggregation: one wave per node
    agg_kernel<<<(N * 64 + 255) / 256, 256, 0, stream>>>(rec, rowptr, Y, out, N);
}

// Round 3
// 359.326 us; speedup vs baseline: 2.9451x; 1.8141x over previous
//
#include <hip/hip_runtime.h>
#include <hip/hip_bf16.h>

#define ALPHA 0.2f
typedef unsigned int uint32;

static __device__ __forceinline__ unsigned short f2bf(float f) {
    unsigned int u = __float_as_uint(f);
    u += 0x7fffu + ((u >> 16) & 1u);          // RNE
    return (unsigned short)(u >> 16);
}
static __device__ __forceinline__ float bflo(uint32 u) { return __uint_as_float(u << 16); }
static __device__ __forceinline__ float bfhi(uint32 u) { return __uint_as_float(u & 0xffff0000u); }

// ---------------------------------------------------------------------------
// mm2: C[M, ldc] (col offset 128*blockIdx.y) = A[M,128] @ B_k[128,128]
// 64 rows x 128 cols per block, 256 threads, 8x4 register tile.
// As[64][36] row-major (pad 36 keeps b128 16B-aligned, reads are 2-way
// wave-broadcast -> conflict-free). Per 4 k-steps: 12 ds_read_b128 vs
// 128 FMAs -> FMA-bound.
// ---------------------------------------------------------------------------
template <int BF16OUT>
__global__ __launch_bounds__(256) void mm2_kernel(const float* __restrict__ A,
                                                  const float* __restrict__ B,
                                                  void* __restrict__ Cv,
                                                  int M, int ldc) {
    __shared__ float Bs[32 * 128];  // [kk][c]
    __shared__ float As[64 * 36];   // [r][kk], padded
    const int tid  = threadIdx.x;
    const int tx   = tid & 31;      // col group: cols tx*4..tx*4+3
    const int ty   = tid >> 5;      // row group: rows ty*8..ty*8+7
    const int row0 = blockIdx.x * 64;
    const int kblk = blockIdx.y;
    const float* Bk = B + (size_t)kblk * 128 * 128;
    const int coff  = kblk * 128;
    const int c0    = tx * 4;

    float4 acc[8];
#pragma unroll
    for (int j = 0; j < 8; ++j) acc[j] = make_float4(0.f, 0.f, 0.f, 0.f);

    const float4* A4 = (const float4*)A;
    const float4* B4 = (const float4*)Bk;

    for (int kb = 0; kb < 128; kb += 32) {
        // Bs: 32x128 = 1024 float4, 4/thread
        for (int i = tid; i < 1024; i += 256)
            ((float4*)Bs)[i] = B4[((size_t)(kb + (i >> 5))) * 32 + (i & 31)];
        // As: 64 rows x 32 k = 512 float4, 2/thread
        for (int i = tid; i < 512; i += 256) {
            int r = i >> 3, k4 = i & 7;
            int rg = row0 + r;
            float4 v = make_float4(0.f, 0.f, 0.f, 0.f);
            if (rg < M) v = A4[(size_t)rg * 32 + (kb >> 2) + k4];
            *(float4*)(As + r * 36 + k4 * 4) = v;
        }
        __syncthreads();
#pragma unroll
        for (int kk = 0; kk < 32; kk += 4) {
            float4 a4[8];
#pragma unroll
            for (int j = 0; j < 8; ++j)
                a4[j] = *(const float4*)(As + (ty * 8 + j) * 36 + kk);
#pragma unroll
            for (int q = 0; q < 4; ++q) {
                float4 b = *(const float4*)(Bs + (kk + q) * 128 + c0);
#pragma unroll
                for (int j = 0; j < 8; ++j) {
                    float a = (q == 0) ? a4[j].x : (q == 1) ? a4[j].y
                              : (q == 2) ? a4[j].z : a4[j].w;
                    acc[j].x += a * b.x; acc[j].y += a * b.y;
                    acc[j].z += a * b.z; acc[j].w += a * b.w;
                }
            }
        }
        __syncthreads();
    }
#pragma unroll
    for (int j = 0; j < 8; ++j) {
        int rg = row0 + ty * 8 + j;
        if (rg >= M) continue;
        if (BF16OUT) {
            ushort4 o;
            o.x = f2bf(acc[j].x); o.y = f2bf(acc[j].y);
            o.z = f2bf(acc[j].z); o.w = f2bf(acc[j].w);
            *(ushort4*)((unsigned short*)Cv + (size_t)rg * ldc + coff + c0) = o;
        } else {
            *(float4*)((float*)Cv + (size_t)rg * ldc + coff + c0) = acc[j];
        }
    }
}

// ---------------------------------------------------------------------------
// scores: one wave per node, s1[n]=dot(Wh[n],a1), s2[n]=dot(Wh[n],a2)
// ---------------------------------------------------------------------------
__global__ __launch_bounds__(256) void scores_kernel(const float* __restrict__ Wh,
                                                     const float* __restrict__ a1,
                                                     const float* __restrict__ a2,
                                                     float* __restrict__ s1,
                                                     float* __restrict__ s2, int N) {
    int wid  = (blockIdx.x * blockDim.x + threadIdx.x) >> 6;
    int lane = threadIdx.x & 63;
    if (wid >= N) return;
    const float* row = Wh + (size_t)wid * 128;
    float v0 = row[lane], v1 = row[64 + lane];
    float x1 = v0 * a1[lane] + v1 * a1[64 + lane];
    float x2 = v0 * a2[lane] + v1 * a2[64 + lane];
#pragma unroll
    for (int off = 32; off > 0; off >>= 1) {
        x1 += __shfl_down(x1, off);
        x2 += __shfl_down(x2, off);
    }
    if (lane == 0) { s1[wid] = x1; s2[wid] = x2; }
}

// ---------------------------------------------------------------------------
// hist: counts[dst]++ per edge AND record slot-within-node -> scatter needs
// no atomics.
// ---------------------------------------------------------------------------
__global__ __launch_bounds__(256) void hist_kernel(const int* __restrict__ ei,
                                                   int* __restrict__ counts,
                                                   int* __restrict__ eslot, int E) {
    int e = blockIdx.x * blockDim.x + threadIdx.x;
    if (e < E) eslot[e] = atomicAdd(&counts[ei[E + e]], 1);
}

// ---------------------------------------------------------------------------
// parallel scan over counts (chunk = 1024): scan1 per-chunk sums,
// scan2 scans chunk sums (<=64 chunks), scan3 writes rowptr.
// ---------------------------------------------------------------------------
__global__ __launch_bounds__(256) void scan1_kernel(const int* __restrict__ counts,
                                                    int* __restrict__ csum, int N) {
    __shared__ int wsums[4];
    const int tid = threadIdx.x, lane = tid & 63, wv = tid >> 6;
    int i0 = blockIdx.x * 1024 + tid * 4;
    int s = 0;
    if (i0 + 3 < N) {
        int4 v = *(const int4*)(counts + i0);
        s = v.x + v.y + v.z + v.w;
    } else {
        for (int q = 0; q < 4; ++q) if (i0 + q < N) s += counts[i0 + q];
    }
#pragma unroll
    for (int off = 32; off > 0; off >>= 1) s += __shfl_down(s, off);
    if (lane == 0) wsums[wv] = s;
    __syncthreads();
    if (tid == 0) csum[blockIdx.x] = wsums[0] + wsums[1] + wsums[2] + wsums[3];
}

__global__ void scan2_kernel(const int* __restrict__ csum, int* __restrict__ coff,
                             int* __restrict__ rowptr, int nchunk, int N, int E) {
    int tid = threadIdx.x;  // 64 threads
    int v = (tid < nchunk) ? csum[tid] : 0;
    int incl = v;
#pragma unroll
    for (int off = 1; off < 64; off <<= 1) {
        int t = __shfl_up(incl, off);
        if (tid >= off) incl += t;
    }
    if (tid < nchunk) coff[tid] = incl - v;
    if (tid == 0) rowptr[N] = E;
}

__global__ __launch_bounds__(256) void scan3_kernel(const int* __restrict__ counts,
                                                    const int* __restrict__ coff,
                                                    int* __restrict__ rowptr, int N) {
    __shared__ int wsums[4];
    const int tid = threadIdx.x, lane = tid & 63, wv = tid >> 6;
    int i0 = blockIdx.x * 1024 + tid * 4;
    int v0 = 0, v1 = 0, v2 = 0, v3 = 0;
    if (i0 + 3 < N) {
        int4 v = *(const int4*)(counts + i0);
        v0 = v.x; v1 = v.y; v2 = v.z; v3 = v.w;
    } else {
        if (i0 + 0 < N) v0 = counts[i0 + 0];
        if (i0 + 1 < N) v1 = counts[i0 + 1];
        if (i0 + 2 < N) v2 = counts[i0 + 2];
        if (i0 + 3 < N) v3 = counts[i0 + 3];
    }
    int tt = v0 + v1 + v2 + v3;
    int incl = tt;
#pragma unroll
    for (int off = 1; off < 64; off <<= 1) {
        int t = __shfl_up(incl, off);
        if (lane >= off) incl += t;
    }
    if (lane == 63) wsums[wv] = incl;
    __syncthreads();
    int woff = 0;
    for (int w2 = 0; w2 < wv; ++w2) woff += wsums[w2];
    int base = coff[blockIdx.x] + woff + (incl - tt);
    if (i0 + 0 < N) rowptr[i0 + 0] = base;
    if (i0 + 1 < N) rowptr[i0 + 1] = base + v0;
    if (i0 + 2 < N) rowptr[i0 + 2] = base + v0 + v1;
    if (i0 + 3 < N) rowptr[i0 + 3] = base + v0 + v1 + v2;
}

// ---------------------------------------------------------------------------
// scatter: pos = rowptr[dst] + eslot[e]; write {ex0,ex1,ex2,src}. No atomics.
// Max-shift skipped: softmax shift-invariant, scores bounded, eps negligible.
// ---------------------------------------------------------------------------
__global__ __launch_bounds__(256) void scatter_kernel(const int* __restrict__ ei,
                                                      const float* __restrict__ ef,
                                                      const float* __restrict__ s1,
                                                      const float* __restrict__ s2,
                                                      const int* __restrict__ rowptr,
                                                      const int* __restrict__ eslot,
                                                      float4* __restrict__ rec, int E) {
    int e = blockIdx.x * blockDim.x + threadIdx.x;
    if (e >= E) return;
    int src = ei[e];
    int dst = ei[E + e];
    float s = s1[src] + s2[dst];
    s = (s >= 0.f) ? s : ALPHA * s;
    float ex0 = __expf(s * ef[e * 3 + 0]);
    float ex1 = __expf(s * ef[e * 3 + 1]);
    float ex2 = __expf(s * ef[e * 3 + 2]);
    int pos = rowptr[dst] + eslot[e];
    rec[pos] = make_float4(ex0, ex1, ex2, __int_as_float(src));
}

// ---------------------------------------------------------------------------
// agg: one wave per node, atomic-free. Pass 1 sums softmax denominators
// (broadcast 16B loads). Pass 2 gathers bf16 Y rows (768B/edge, uint32 =
// bf16x2 per lane) unrolled x2 for MLP; fp32 accumulate; one float2 store.
// ---------------------------------------------------------------------------
__global__ __launch_bounds__(256) void agg_kernel(const float4* __restrict__ rec,
                                                  const int* __restrict__ rowptr,
                                                  const uint32* __restrict__ Yu,
                                                  float* __restrict__ out, int N) {
    int node = (blockIdx.x * blockDim.x + threadIdx.x) >> 6;
    int lane = threadIdx.x & 63;
    if (node >= N) return;
    int beg = rowptr[node], end = rowptr[node + 1];

    float d0 = 0.f, d1 = 0.f, d2 = 0.f;
    for (int j = beg; j < end; ++j) {
        float4 r = rec[j];
        d0 += r.x; d1 += r.y; d2 += r.z;
    }
    float inv0 = 1.f / (d0 + 1e-16f);
    float inv1 = 1.f / (d1 + 1e-16f);
    float inv2 = 1.f / (d2 + 1e-16f);

    float a0 = 0.f, a1 = 0.f;
    int j = beg;
    for (; j + 1 < end; j += 2) {
        float4 r0 = rec[j], r1 = rec[j + 1];
        const uint32* p0 = Yu + (size_t)__float_as_int(r0.w) * 192;
        const uint32* p1 = Yu + (size_t)__float_as_int(r1.w) * 192;
        uint32 u00 = p0[lane], u01 = p0[64 + lane], u02 = p0[128 + lane];
        uint32 u10 = p1[lane], u11 = p1[64 + lane], u12 = p1[128 + lane];
        float w00 = r0.x * inv0, w01 = r0.y * inv1, w02 = r0.z * inv2;
        float w10 = r1.x * inv0, w11 = r1.y * inv1, w12 = r1.z * inv2;
        a0 += w00 * bflo(u00) + w01 * bflo(u01) + w02 * bflo(u02);
        a1 += w00 * bfhi(u00) + w01 * bfhi(u01) + w02 * bfhi(u02);
        a0 += w10 * bflo(u10) + w11 * bflo(u11) + w12 * bflo(u12);
        a1 += w10 * bfhi(u10) + w11 * bfhi(u11) + w12 * bfhi(u12);
    }
    if (j < end) {
        float4 r0 = rec[j];
        const uint32* p0 = Yu + (size_t)__float_as_int(r0.w) * 192;
        uint32 u00 = p0[lane], u01 = p0[64 + lane], u02 = p0[128 + lane];
        float w00 = r0.x * inv0, w01 = r0.y * inv1, w02 = r0.z * inv2;
        a0 += w00 * bflo(u00) + w01 * bflo(u01) + w02 * bflo(u02);
        a1 += w00 * bfhi(u00) + w01 * bfhi(u01) + w02 * bfhi(u02);
    }
    ((float2*)(out + (size_t)node * 128))[lane] = make_float2(a0, a1);
}

// ---------------------------------------------------------------------------
extern "C" void kernel_launch(void* const* d_in, const int* in_sizes, int n_in,
                              void* d_out, int out_size, void* d_ws, size_t ws_size,
                              hipStream_t stream) {
    const float* h    = (const float*)d_in[0];
    const int*   ei   = (const int*)d_in[1];    // [2, E]
    const float* ef   = (const float*)d_in[2];  // [E, 3]
    const float* W    = (const float*)d_in[3];  // [128,128]
    const float* a1   = (const float*)d_in[4];  // [128]
    const float* a2   = (const float*)d_in[5];  // [128]
    const float* Wout = (const float*)d_in[6];  // [384,128]
    float*       out  = (float*)d_out;

    const int N = in_sizes[0] / 128;  // 50000
    const int E = in_sizes[2] / 3;    // 800000
    const int nchunk = (N + 1023) / 1024;

    // workspace layout (all 16B-aligned where vector-accessed)
    float* ws   = (float*)d_ws;
    float* Wh   = ws;                                   // N*128 f32
    float* s1   = Wh + (size_t)N * 128;                 // N
    float* s2   = s1 + N;                               // N
    float4* rec = (float4*)(s2 + N);                    // E * 16B
    unsigned short* Yb = (unsigned short*)(rec + E);    // N*384 bf16
    int* counts = (int*)(Yb + (size_t)N * 384);         // N
    int* rowptr = counts + N;                           // N+1
    int* eslot  = rowptr + N + 1;                       // E
    int* csum   = eslot + E;                            // nchunk
    int* coff   = csum + 64;                            // nchunk

    hipMemsetAsync(counts, 0, (size_t)N * sizeof(int), stream);

    const int mblocks = (N + 63) / 64;
    mm2_kernel<0><<<dim3(mblocks, 1), 256, 0, stream>>>(h, W, (void*)Wh, N, 128);
    mm2_kernel<1><<<dim3(mblocks, 3), 256, 0, stream>>>(Wh, Wout, (void*)Yb, N, 384);
    scores_kernel<<<(N * 64 + 255) / 256, 256, 0, stream>>>(Wh, a1, a2, s1, s2, N);
    hist_kernel<<<(E + 255) / 256, 256, 0, stream>>>(ei, counts, eslot, E);
    scan1_kernel<<<nchunk, 256, 0, stream>>>(counts, csum, N);
    scan2_kernel<<<1, 64, 0, stream>>>(csum, coff, rowptr, nchunk, N, E);
    scan3_kernel<<<nchunk, 256, 0, stream>>>(counts, coff, rowptr, N);
    scatter_kernel<<<(E + 255) / 256, 256, 0, stream>>>(ei, ef, s1, s2, rowptr, eslot, rec, E);
    agg_kernel<<<(N * 64 + 255) / 256, 256, 0, stream>>>(rec, rowptr, (const uint32*)Yb, out, N);
}

// Round 4
// 296.342 us; speedup vs baseline: 3.5710x; 1.2125x over previous
//
#include <hip/hip_runtime.h>
#include <hip/hip_bf16.h>

#define ALPHA 0.2f
typedef unsigned int uint32;
typedef __attribute__((ext_vector_type(8))) short short8;   // 8 bf16 = 4 VGPRs
typedef __attribute__((ext_vector_type(4))) float f32x4;

static __device__ __forceinline__ unsigned short f2bf(float f) {
    unsigned int u = __float_as_uint(f);
    u += 0x7fffu + ((u >> 16) & 1u);          // RNE
    return (unsigned short)(u >> 16);
}
static __device__ __forceinline__ float bflo(uint32 u) { return __uint_as_float(u << 16); }
static __device__ __forceinline__ float bfhi(uint32 u) { return __uint_as_float(u & 0xffff0000u); }

// ---------------------------------------------------------------------------
// mmwh: Whb[M,128](bf16) = h @ W, with s1/s2 (fp32) fused in the epilogue.
// fp32 vector-ALU GEMM (h must be read fp32; only 1.6 GFLOP). 64x128 tile,
// 8x4 register tile. Each block owns complete rows -> row-dot with a1/a2
// reduced across the 32 col-threads (width-32 shuffle).
// ---------------------------------------------------------------------------
__global__ __launch_bounds__(256) void mmwh_kernel(const float* __restrict__ A,
                                                   const float* __restrict__ B,
                                                   const float* __restrict__ a1,
                                                   const float* __restrict__ a2,
                                                   unsigned short* __restrict__ Whb,
                                                   float* __restrict__ s1,
                                                   float* __restrict__ s2, int M) {
    __shared__ float Bs[32 * 128];  // [kk][c]
    __shared__ float As[64 * 36];   // [r][kk], padded
    const int tid  = threadIdx.x;
    const int tx   = tid & 31;      // cols tx*4..tx*4+3
    const int ty   = tid >> 5;      // rows ty*8..ty*8+7
    const int row0 = blockIdx.x * 64;
    const int c0   = tx * 4;

    float4 acc[8];
#pragma unroll
    for (int j = 0; j < 8; ++j) acc[j] = make_float4(0.f, 0.f, 0.f, 0.f);

    const float4* A4 = (const float4*)A;
    const float4* B4 = (const float4*)B;

    for (int kb = 0; kb < 128; kb += 32) {
        for (int i = tid; i < 1024; i += 256)
            ((float4*)Bs)[i] = B4[((size_t)(kb + (i >> 5))) * 32 + (i & 31)];
        for (int i = tid; i < 512; i += 256) {
            int r = i >> 3, k4 = i & 7;
            int rg = row0 + r;
            float4 v = make_float4(0.f, 0.f, 0.f, 0.f);
            if (rg < M) v = A4[(size_t)rg * 32 + (kb >> 2) + k4];
            *(float4*)(As + r * 36 + k4 * 4) = v;
        }
        __syncthreads();
#pragma unroll
        for (int kk = 0; kk < 32; kk += 4) {
            float4 a4[8];
#pragma unroll
            for (int j = 0; j < 8; ++j)
                a4[j] = *(const float4*)(As + (ty * 8 + j) * 36 + kk);
#pragma unroll
            for (int q = 0; q < 4; ++q) {
                float4 b = *(const float4*)(Bs + (kk + q) * 128 + c0);
#pragma unroll
                for (int j = 0; j < 8; ++j) {
                    float a = (q == 0) ? a4[j].x : (q == 1) ? a4[j].y
                              : (q == 2) ? a4[j].z : a4[j].w;
                    acc[j].x += a * b.x; acc[j].y += a * b.y;
                    acc[j].z += a * b.z; acc[j].w += a * b.w;
                }
            }
        }
        __syncthreads();
    }
    // epilogue: bf16 store + fused scores
    float4 w1 = *(const float4*)(a1 + c0);
    float4 w2 = *(const float4*)(a2 + c0);
#pragma unroll
    for (int j = 0; j < 8; ++j) {
        int rg = row0 + ty * 8 + j;
        float x1 = acc[j].x * w1.x + acc[j].y * w1.y + acc[j].z * w1.z + acc[j].w * w1.w;
        float x2 = acc[j].x * w2.x + acc[j].y * w2.y + acc[j].z * w2.z + acc[j].w * w2.w;
#pragma unroll
        for (int off = 16; off > 0; off >>= 1) {
            x1 += __shfl_down(x1, off, 32);
            x2 += __shfl_down(x2, off, 32);
        }
        if (rg < M) {
            ushort4 o;
            o.x = f2bf(acc[j].x); o.y = f2bf(acc[j].y);
            o.z = f2bf(acc[j].z); o.w = f2bf(acc[j].w);
            *(ushort4*)(Whb + (size_t)rg * 128 + c0) = o;
            if (tx == 0) { s1[rg] = x1; s2[rg] = x2; }
        }
    }
}

// ---------------------------------------------------------------------------
// prep: WT[slice][n][k] = bf16(Wout[slice*128+k][n]) — B transposed to
// MFMA-friendly [n][k] rows. Tiny (49152 elements), runs once per launch.
// ---------------------------------------------------------------------------
__global__ __launch_bounds__(256) void prep_kernel(const float* __restrict__ Wout,
                                                   unsigned short* __restrict__ WT) {
    int i = blockIdx.x * 256 + threadIdx.x;
    if (i >= 3 * 128 * 128) return;
    int s = i >> 14;
    int n = (i >> 7) & 127;
    int k = i & 127;
    WT[i] = f2bf(Wout[(size_t)(s * 128 + k) * 128 + n]);
}

// ---------------------------------------------------------------------------
// mmy: Yb[M, 384] slice ks = Whb @ WT[ks]  via 16x16x32 bf16 MFMA.
// Block: 128 rows x 128 cols, 4 waves (wave w = rows w*32..w*32+31).
// Full K=128 staged once in LDS (As 32KB + Bs 32KB), XOR-swizzled 16B
// groups: phys_group = g ^ (row&15) -> fragment reads <=2-way bank alias.
// Fragment layouts (HW-verified m89/m120): A[m=lane&15][k=quad*8+j],
// B^T rows likewise; D: col=lane&15, row=quad*4+reg.
// ---------------------------------------------------------------------------
__global__ __launch_bounds__(256) void mmy_kernel(const unsigned short* __restrict__ Whb,
                                                  const unsigned short* __restrict__ WT,
                                                  unsigned short* __restrict__ Yb,
                                                  int M) {
    __shared__ unsigned short As[128 * 128];
    __shared__ unsigned short Bs[128 * 128];
    const int tid  = threadIdx.x;
    const int lane = tid & 63;
    const int w    = tid >> 6;
    const int row0 = blockIdx.x * 128;
    const int ks   = blockIdx.y;
    const unsigned short* WTs = WT + ks * 16384;

    for (int i = tid; i < 2048; i += 256) {       // As: 128 rows x 16 groups
        int r = i >> 4, g = i & 15;
        int rg = row0 + r;
        uint4 v = make_uint4(0u, 0u, 0u, 0u);
        if (rg < M) v = *(const uint4*)(Whb + (size_t)rg * 128 + g * 8);
        *(uint4*)(As + r * 128 + ((g ^ (r & 15)) * 8)) = v;
    }
    for (int i = tid; i < 2048; i += 256) {       // Bs: B^T rows
        int r = i >> 4, g = i & 15;
        uint4 v = *(const uint4*)(WTs + r * 128 + g * 8);
        *(uint4*)(Bs + r * 128 + ((g ^ (r & 15)) * 8)) = v;
    }
    __syncthreads();

    f32x4 acc[2][8];
#pragma unroll
    for (int mt = 0; mt < 2; ++mt)
#pragma unroll
        for (int nt = 0; nt < 8; ++nt) acc[mt][nt] = (f32x4){0.f, 0.f, 0.f, 0.f};

    const int ml   = lane & 15;
    const int quad = lane >> 4;
#pragma unroll
    for (int kc = 0; kc < 4; ++kc) {
        int gl = ((kc * 4 + quad) ^ ml) * 8;
        short8 af0 = *(const short8*)(As + (w * 32 + ml) * 128 + gl);
        short8 af1 = *(const short8*)(As + (w * 32 + 16 + ml) * 128 + gl);
#pragma unroll
        for (int nt = 0; nt < 8; ++nt) {
            short8 bf = *(const short8*)(Bs + (nt * 16 + ml) * 128 + gl);
            acc[0][nt] = __builtin_amdgcn_mfma_f32_16x16x32_bf16(af0, bf, acc[0][nt], 0, 0, 0);
            acc[1][nt] = __builtin_amdgcn_mfma_f32_16x16x32_bf16(af1, bf, acc[1][nt], 0, 0, 0);
        }
    }
#pragma unroll
    for (int mt = 0; mt < 2; ++mt) {
        int rbase = row0 + w * 32 + mt * 16 + quad * 4;
#pragma unroll
        for (int r = 0; r < 4; ++r) {
            int rg = rbase + r;
            if (rg >= M) continue;
            unsigned short* yrow = Yb + (size_t)rg * 384 + ks * 128 + ml;
#pragma unroll
            for (int nt = 0; nt < 8; ++nt)
                yrow[nt * 16] = f2bf(acc[mt][nt][r]);
        }
    }
}

// ---------------------------------------------------------------------------
// hist: counts[dst]++ per edge AND record slot-within-node.
// ---------------------------------------------------------------------------
__global__ __launch_bounds__(256) void hist_kernel(const int* __restrict__ ei,
                                                   int* __restrict__ counts,
                                                   int* __restrict__ eslot, int E) {
    int e = blockIdx.x * blockDim.x + threadIdx.x;
    if (e < E) eslot[e] = atomicAdd(&counts[ei[E + e]], 1);
}

// ---------------------------------------------------------------------------
// parallel scan over counts (chunk = 1024)
// ---------------------------------------------------------------------------
__global__ __launch_bounds__(256) void scan1_kernel(const int* __restrict__ counts,
                                                    int* __restrict__ csum, int N) {
    __shared__ int wsums[4];
    const int tid = threadIdx.x, lane = tid & 63, wv = tid >> 6;
    int i0 = blockIdx.x * 1024 + tid * 4;
    int s = 0;
    if (i0 + 3 < N) {
        int4 v = *(const int4*)(counts + i0);
        s = v.x + v.y + v.z + v.w;
    } else {
        for (int q = 0; q < 4; ++q) if (i0 + q < N) s += counts[i0 + q];
    }
#pragma unroll
    for (int off = 32; off > 0; off >>= 1) s += __shfl_down(s, off);
    if (lane == 0) wsums[wv] = s;
    __syncthreads();
    if (tid == 0) csum[blockIdx.x] = wsums[0] + wsums[1] + wsums[2] + wsums[3];
}

__global__ void scan2_kernel(const int* __restrict__ csum, int* __restrict__ coff,
                             int* __restrict__ rowptr, int nchunk, int N, int E) {
    int tid = threadIdx.x;  // 64 threads
    int v = (tid < nchunk) ? csum[tid] : 0;
    int incl = v;
#pragma unroll
    for (int off = 1; off < 64; off <<= 1) {
        int t = __shfl_up(incl, off);
        if (tid >= off) incl += t;
    }
    if (tid < nchunk) coff[tid] = incl - v;
    if (tid == 0) rowptr[N] = E;
}

__global__ __launch_bounds__(256) void scan3_kernel(const int* __restrict__ counts,
                                                    const int* __restrict__ coff,
                                                    int* __restrict__ rowptr, int N) {
    __shared__ int wsums[4];
    const int tid = threadIdx.x, lane = tid & 63, wv = tid >> 6;
    int i0 = blockIdx.x * 1024 + tid * 4;
    int v0 = 0, v1 = 0, v2 = 0, v3 = 0;
    if (i0 + 3 < N) {
        int4 v = *(const int4*)(counts + i0);
        v0 = v.x; v1 = v.y; v2 = v.z; v3 = v.w;
    } else {
        if (i0 + 0 < N) v0 = counts[i0 + 0];
        if (i0 + 1 < N) v1 = counts[i0 + 1];
        if (i0 + 2 < N) v2 = counts[i0 + 2];
        if (i0 + 3 < N) v3 = counts[i0 + 3];
    }
    int tt = v0 + v1 + v2 + v3;
    int incl = tt;
#pragma unroll
    for (int off = 1; off < 64; off <<= 1) {
        int t = __shfl_up(incl, off);
        if (lane >= off) incl += t;
    }
    if (lane == 63) wsums[wv] = incl;
    __syncthreads();
    int woff = 0;
    for (int w2 = 0; w2 < wv; ++w2) woff += wsums[w2];
    int base = coff[blockIdx.x] + woff + (incl - tt);
    if (i0 + 0 < N) rowptr[i0 + 0] = base;
    if (i0 + 1 < N) rowptr[i0 + 1] = base + v0;
    if (i0 + 2 < N) rowptr[i0 + 2] = base + v0 + v1;
    if (i0 + 3 < N) rowptr[i0 + 3] = base + v0 + v1 + v2;
}

// ---------------------------------------------------------------------------
// scatter: pos = rowptr[dst] + eslot[e]; write {ex0,ex1,ex2,src}. No atomics.
// Max-shift skipped: softmax shift-invariant, scores bounded, eps negligible.
// ---------------------------------------------------------------------------
__global__ __launch_bounds__(256) void scatter_kernel(const int* __restrict__ ei,
                                                      const float* __restrict__ ef,
                                                      const float* __restrict__ s1,
                                                      const float* __restrict__ s2,
                                                      const int* __restrict__ rowptr,
                                                      const int* __restrict__ eslot,
                                                      float4* __restrict__ rec, int E) {
    int e = blockIdx.x * blockDim.x + threadIdx.x;
    if (e >= E) return;
    int src = ei[e];
    int dst = ei[E + e];
    float s = s1[src] + s2[dst];
    s = (s >= 0.f) ? s : ALPHA * s;
    float ex0 = __expf(s * ef[e * 3 + 0]);
    float ex1 = __expf(s * ef[e * 3 + 1]);
    float ex2 = __expf(s * ef[e * 3 + 2]);
    int pos = rowptr[dst] + eslot[e];
    rec[pos] = make_float4(ex0, ex1, ex2, __int_as_float(src));
}

// ---------------------------------------------------------------------------
// agg: one wave per node, atomic-free. Denominators: lane-parallel over the
// CSR segment + xor-butterfly reduce. Main: x4-unrolled gather of bf16 Y
// rows (768B/edge), fp32 accumulate, one float2 store per lane.
// ---------------------------------------------------------------------------
__global__ __launch_bounds__(256) void agg_kernel(const float4* __restrict__ rec,
                                                  const int* __restrict__ rowptr,
                                                  const uint32* __restrict__ Yu,
                                                  float* __restrict__ out, int N) {
    int node = (blockIdx.x * blockDim.x + threadIdx.x) >> 6;
    int lane = threadIdx.x & 63;
    if (node >= N) return;
    int beg = rowptr[node], end = rowptr[node + 1];

    float d0 = 0.f, d1 = 0.f, d2 = 0.f;
    for (int jb = beg + lane; jb < end; jb += 64) {
        float4 r = rec[jb];
        d0 += r.x; d1 += r.y; d2 += r.z;
    }
#pragma unroll
    for (int off = 32; off > 0; off >>= 1) {
        d0 += __shfl_xor(d0, off);
        d1 += __shfl_xor(d1, off);
        d2 += __shfl_xor(d2, off);
    }
    float inv0 = 1.f / (d0 + 1e-16f);
    float inv1 = 1.f / (d1 + 1e-16f);
    float inv2 = 1.f / (d2 + 1e-16f);

    float a0 = 0.f, a1 = 0.f;
    int j = beg;
    for (; j + 3 < end; j += 4) {
        float4 r0 = rec[j], r1 = rec[j + 1], r2 = rec[j + 2], r3 = rec[j + 3];
        const uint32* p0 = Yu + (size_t)__float_as_int(r0.w) * 192;
        const uint32* p1 = Yu + (size_t)__float_as_int(r1.w) * 192;
        const uint32* p2 = Yu + (size_t)__float_as_int(r2.w) * 192;
        const uint32* p3 = Yu + (size_t)__float_as_int(r3.w) * 192;
        uint32 u00 = p0[lane], u01 = p0[64 + lane], u02 = p0[128 + lane];
        uint32 u10 = p1[lane], u11 = p1[64 + lane], u12 = p1[128 + lane];
        uint32 u20 = p2[lane], u21 = p2[64 + lane], u22 = p2[128 + lane];
        uint32 u30 = p3[lane], u31 = p3[64 + lane], u32 = p3[128 + lane];
        float w00 = r0.x * inv0, w01 = r0.y * inv1, w02 = r0.z * inv2;
        float w10 = r1.x * inv0, w11 = r1.y * inv1, w12 = r1.z * inv2;
        float w20 = r2.x * inv0, w21 = r2.y * inv1, w22 = r2.z * inv2;
        float w30 = r3.x * inv0, w31 = r3.y * inv1, w32 = r3.z * inv2;
        a0 += w00 * bflo(u00) + w01 * bflo(u01) + w02 * bflo(u02);
        a1 += w00 * bfhi(u00) + w01 * bfhi(u01) + w02 * bfhi(u02);
        a0 += w10 * bflo(u10) + w11 * bflo(u11) + w12 * bflo(u12);
        a1 += w10 * bfhi(u10) + w11 * bfhi(u11) + w12 * bfhi(u12);
        a0 += w20 * bflo(u20) + w21 * bflo(u21) + w22 * bflo(u22);
        a1 += w20 * bfhi(u20) + w21 * bfhi(u21) + w22 * bfhi(u22);
        a0 += w30 * bflo(u30) + w31 * bflo(u31) + w32 * bflo(u32);
        a1 += w30 * bfhi(u30) + w31 * bfhi(u31) + w32 * bfhi(u32);
    }
    for (; j < end; ++j) {
        float4 r0 = rec[j];
        const uint32* p0 = Yu + (size_t)__float_as_int(r0.w) * 192;
        uint32 u00 = p0[lane], u01 = p0[64 + lane], u02 = p0[128 + lane];
        float w00 = r0.x * inv0, w01 = r0.y * inv1, w02 = r0.z * inv2;
        a0 += w00 * bflo(u00) + w01 * bflo(u01) + w02 * bflo(u02);
        a1 += w00 * bfhi(u00) + w01 * bfhi(u01) + w02 * bfhi(u02);
    }
    ((float2*)(out + (size_t)node * 128))[lane] = make_float2(a0, a1);
}

// ---------------------------------------------------------------------------
extern "C" void kernel_launch(void* const* d_in, const int* in_sizes, int n_in,
                              void* d_out, int out_size, void* d_ws, size_t ws_size,
                              hipStream_t stream) {
    const float* h    = (const float*)d_in[0];
    const int*   ei   = (const int*)d_in[1];    // [2, E]
    const float* ef   = (const float*)d_in[2];  // [E, 3]
    const float* W    = (const float*)d_in[3];  // [128,128]
    const float* a1   = (const float*)d_in[4];  // [128]
    const float* a2   = (const float*)d_in[5];  // [128]
    const float* Wout = (const float*)d_in[6];  // [384,128]
    float*       out  = (float*)d_out;

    const int N = in_sizes[0] / 128;  // 50000
    const int E = in_sizes[2] / 3;    // 800000
    const int nchunk = (N + 1023) / 1024;

    // workspace layout (16B-aligned where vector-accessed)
    unsigned short* Whb = (unsigned short*)d_ws;        // N*128 bf16
    float* s1   = (float*)(Whb + (size_t)N * 128);      // N
    float* s2   = s1 + N;                               // N
    float4* rec = (float4*)(s2 + N);                    // E * 16B
    unsigned short* Yb = (unsigned short*)(rec + E);    // N*384 bf16
    unsigned short* WT = Yb + (size_t)N * 384;          // 3*128*128 bf16
    int* counts = (int*)(WT + 3 * 128 * 128);           // N
    int* rowptr = counts + N;                           // N+1
    int* eslot  = rowptr + N + 1;                       // E
    int* csum   = eslot + E;                            // nchunk (<=64)
    int* coff   = csum + 64;                            // nchunk

    hipMemsetAsync(counts, 0, (size_t)N * sizeof(int), stream);

    mmwh_kernel<<<(N + 63) / 64, 256, 0, stream>>>(h, W, a1, a2, Whb, s1, s2, N);
    prep_kernel<<<192, 256, 0, stream>>>(Wout, WT);
    mmy_kernel<<<dim3((N + 127) / 128, 3), 256, 0, stream>>>(Whb, WT, Yb, N);
    hist_kernel<<<(E + 255) / 256, 256, 0, stream>>>(ei, counts, eslot, E);
    scan1_kernel<<<nchunk, 256, 0, stream>>>(counts, csum, N);
    scan2_kernel<<<1, 64, 0, stream>>>(csum, coff, rowptr, nchunk, N, E);
    scan3_kernel<<<nchunk, 256, 0, stream>>>(counts, coff, rowptr, N);
    scatter_kernel<<<(E + 255) / 256, 256, 0, stream>>>(ei, ef, s1, s2, rowptr, eslot, rec, E);
    agg_kernel<<<(N * 64 + 255) / 256, 256, 0, stream>>>(rec, rowptr, (const uint32*)Yb, out, N);
}

// Round 5
// 261.997 us; speedup vs baseline: 4.0392x; 1.1311x over previous
//
#include <hip/hip_runtime.h>
#include <hip/hip_bf16.h>

#define ALPHA 0.2f
typedef unsigned int uint32;
typedef __attribute__((ext_vector_type(8))) short short8;   // 8 bf16 = 4 VGPRs
typedef __attribute__((ext_vector_type(4))) float f32x4;

static __device__ __forceinline__ unsigned short f2bf(float f) {
    unsigned int u = __float_as_uint(f);
    u += 0x7fffu + ((u >> 16) & 1u);          // RNE
    return (unsigned short)(u >> 16);
}
static __device__ __forceinline__ uint32 pk2bf(float lo, float hi) {
    return (uint32)f2bf(lo) | ((uint32)f2bf(hi) << 16);
}
static __device__ __forceinline__ float bflo(uint32 u) { return __uint_as_float(u << 16); }
static __device__ __forceinline__ float bfhi(uint32 u) { return __uint_as_float(u & 0xffff0000u); }

// ---------------------------------------------------------------------------
// prep2: fold W into everything downstream (associativity: Y_k = h@(W@Wout_k),
// s1 = h@(W@a1)).  Blocks 0..23: WT2[s][n][j] = bf16( sum_c W[j][c] *
// Wout[s*128+c][n] )  (B^T layout for MFMA).  Block 24: w1f[j]=sum_c W[j][c]
// a1[c], w2f likewise (fp32).  W staged transposed in LDS (pad 129).
// ---------------------------------------------------------------------------
__global__ __launch_bounds__(256) void prep2_kernel(const float* __restrict__ W,
                                                    const float* __restrict__ Wout,
                                                    const float* __restrict__ a1,
                                                    const float* __restrict__ a2,
                                                    unsigned short* __restrict__ WT2,
                                                    float* __restrict__ w1f,
                                                    float* __restrict__ w2f) {
    __shared__ float WT_lds[129 * 128];   // [c][j] = W[j][c], pad 129 (~66KB)
    __shared__ float Wos[128 * 16];       // [c][q] Wout slice cols
    const int tid = threadIdx.x;
    for (int i = tid; i < 16384; i += 256) {
        int j = i >> 7, c = i & 127;
        WT_lds[c * 129 + j] = W[i];
    }
    if (blockIdx.x < 24) {
        int s = blockIdx.x >> 3, nb = blockIdx.x & 7;
        for (int i = tid; i < 2048; i += 256) {
            int c = i >> 4, q = i & 15;
            Wos[i] = Wout[(size_t)(s * 128 + c) * 128 + nb * 16 + q];
        }
        __syncthreads();
        int j = tid & 127, nh = tid >> 7;
        float acc[8];
#pragma unroll
        for (int p = 0; p < 8; ++p) acc[p] = 0.f;
        for (int c = 0; c < 128; ++c) {
            float w = WT_lds[c * 129 + j];
#pragma unroll
            for (int p = 0; p < 8; ++p) acc[p] += w * Wos[c * 16 + nh * 8 + p];
        }
#pragma unroll
        for (int p = 0; p < 8; ++p) {
            int n = nb * 16 + nh * 8 + p;
            WT2[((size_t)s * 128 + n) * 128 + j] = f2bf(acc[p]);
        }
    } else {
        __syncthreads();
        if (tid < 128) {
            float acc1 = 0.f, acc2 = 0.f;
            for (int c = 0; c < 128; ++c) {
                float w = WT_lds[c * 129 + tid];
                acc1 += w * a1[c];
                acc2 += w * a2[c];
            }
            w1f[tid] = acc1;
            w2f[tid] = acc2;
        }
    }
}

// ---------------------------------------------------------------------------
// mmy2: Yb[M,384] = bf16(h) @ M_k (all 3 slices per block) via 16x16x32 bf16
// MFMA.  A-tile: h fp32 read once, converted to bf16 during LDS staging;
// s1/s2 = h . w1f/w2f computed fp32 in the SAME staging pass (zero extra
// global traffic), reduced across the 16 threads sharing a row (shfl_xor
// 1/2/4/8).  Bs reloaded per slice (A staged once -> 3x MFMA per A-byte).
// XOR-swizzled 16B groups (verified R4): frag reads <=2-way bank alias.
// ---------------------------------------------------------------------------
__global__ __launch_bounds__(256) void mmy2_kernel(const float* __restrict__ h,
                                                   const unsigned short* __restrict__ WT2,
                                                   const float* __restrict__ w1f,
                                                   const float* __restrict__ w2f,
                                                   unsigned short* __restrict__ Yb,
                                                   float* __restrict__ s1,
                                                   float* __restrict__ s2, int M) {
    __shared__ unsigned short As[128 * 128];
    __shared__ unsigned short Bs[128 * 128];
    __shared__ float ws1[128], ws2[128];
    const int tid  = threadIdx.x;
    const int lane = tid & 63;
    const int w    = tid >> 6;
    const int row0 = blockIdx.x * 128;

    if (tid < 128) ws1[tid] = w1f[tid];
    else           ws2[tid - 128] = w2f[tid - 128];
    __syncthreads();

    // ---- stage A (fp32 -> bf16) + fused fp32 score partials ----
    const float4* h4 = (const float4*)h;
    float sp1[8], sp2[8];
#pragma unroll
    for (int m = 0; m < 8; ++m) { sp1[m] = 0.f; sp2[m] = 0.f; }
#pragma unroll
    for (int m = 0; m < 8; ++m) {
        int i = m * 256 + tid;            // 0..2047
        int r = i >> 4, g = i & 15;
        int rg = row0 + r;
        float4 va = make_float4(0.f, 0.f, 0.f, 0.f), vb = va;
        if (rg < M) {
            va = h4[(size_t)rg * 32 + g * 2];
            vb = h4[(size_t)rg * 32 + g * 2 + 1];
        }
        float4 wa1 = *(const float4*)(ws1 + g * 8);
        float4 wb1 = *(const float4*)(ws1 + g * 8 + 4);
        float4 wa2 = *(const float4*)(ws2 + g * 8);
        float4 wb2 = *(const float4*)(ws2 + g * 8 + 4);
        sp1[m] += va.x * wa1.x + va.y * wa1.y + va.z * wa1.z + va.w * wa1.w
                + vb.x * wb1.x + vb.y * wb1.y + vb.z * wb1.z + vb.w * wb1.w;
        sp2[m] += va.x * wa2.x + va.y * wa2.y + va.z * wa2.z + va.w * wa2.w
                + vb.x * wb2.x + vb.y * wb2.y + vb.z * wb2.z + vb.w * wb2.w;
        uint4 u;
        u.x = pk2bf(va.x, va.y); u.y = pk2bf(va.z, va.w);
        u.z = pk2bf(vb.x, vb.y); u.w = pk2bf(vb.z, vb.w);
        *(uint4*)(As + r * 128 + ((g ^ (r & 15)) * 8)) = u;
    }
    // reduce scores across the 16 threads sharing each row (tid groups of 16)
#pragma unroll
    for (int m = 0; m < 8; ++m) {
#pragma unroll
        for (int off = 1; off < 16; off <<= 1) {
            sp1[m] += __shfl_xor(sp1[m], off);
            sp2[m] += __shfl_xor(sp2[m], off);
        }
    }
    if ((tid & 15) == 0) {
#pragma unroll
        for (int m = 0; m < 8; ++m) {
            int rg = row0 + m * 16 + (tid >> 4);
            if (rg < M) { s1[rg] = sp1[m]; s2[rg] = sp2[m]; }
        }
    }

    const int ml   = lane & 15;
    const int quad = lane >> 4;
    for (int ks = 0; ks < 3; ++ks) {
        __syncthreads();                          // prev compute done / As ready
#pragma unroll
        for (int m = 0; m < 8; ++m) {             // stage Bs = WT2[ks]
            int i = m * 256 + tid;
            int n = i >> 4, g = i & 15;
            uint4 v = *(const uint4*)(WT2 + (size_t)ks * 16384 + n * 128 + g * 8);
            *(uint4*)(Bs + n * 128 + ((g ^ (n & 15)) * 8)) = v;
        }
        __syncthreads();

        f32x4 acc[2][8];
#pragma unroll
        for (int mt = 0; mt < 2; ++mt)
#pragma unroll
            for (int nt = 0; nt < 8; ++nt) acc[mt][nt] = (f32x4){0.f, 0.f, 0.f, 0.f};
#pragma unroll
        for (int kc = 0; kc < 4; ++kc) {
            int gl = ((kc * 4 + quad) ^ ml) * 8;
            short8 af0 = *(const short8*)(As + (w * 32 + ml) * 128 + gl);
            short8 af1 = *(const short8*)(As + (w * 32 + 16 + ml) * 128 + gl);
#pragma unroll
            for (int nt = 0; nt < 8; ++nt) {
                short8 bf = *(const short8*)(Bs + (nt * 16 + ml) * 128 + gl);
                acc[0][nt] = __builtin_amdgcn_mfma_f32_16x16x32_bf16(af0, bf, acc[0][nt], 0, 0, 0);
                acc[1][nt] = __builtin_amdgcn_mfma_f32_16x16x32_bf16(af1, bf, acc[1][nt], 0, 0, 0);
            }
        }
#pragma unroll
        for (int mt = 0; mt < 2; ++mt) {
            int rbase = row0 + w * 32 + mt * 16 + quad * 4;
#pragma unroll
            for (int r = 0; r < 4; ++r) {
                int rg = rbase + r;
                if (rg >= M) continue;
                unsigned short* yrow = Yb + (size_t)rg * 384 + ks * 128 + ml;
#pragma unroll
                for (int nt = 0; nt < 8; ++nt)
                    yrow[nt * 16] = f2bf(acc[mt][nt][r]);
            }
        }
    }
}

// ---------------------------------------------------------------------------
// hist: counts[dst]++ per edge AND record slot-within-node.
// ---------------------------------------------------------------------------
__global__ __launch_bounds__(256) void hist_kernel(const int* __restrict__ ei,
                                                   int* __restrict__ counts,
                                                   int* __restrict__ eslot, int E) {
    int e = blockIdx.x * blockDim.x + threadIdx.x;
    if (e < E) eslot[e] = atomicAdd(&counts[ei[E + e]], 1);
}

// ---------------------------------------------------------------------------
// scan1: per-1024-chunk sums.
// ---------------------------------------------------------------------------
__global__ __launch_bounds__(256) void scan1_kernel(const int* __restrict__ counts,
                                                    int* __restrict__ csum, int N) {
    __shared__ int wsums[4];
    const int tid = threadIdx.x, lane = tid & 63, wv = tid >> 6;
    int i0 = blockIdx.x * 1024 + tid * 4;
    int s = 0;
    if (i0 + 3 < N) {
        int4 v = *(const int4*)(counts + i0);
        s = v.x + v.y + v.z + v.w;
    } else {
        for (int q = 0; q < 4; ++q) if (i0 + q < N) s += counts[i0 + q];
    }
#pragma unroll
    for (int off = 32; off > 0; off >>= 1) s += __shfl_down(s, off);
    if (lane == 0) wsums[wv] = s;
    __syncthreads();
    if (tid == 0) csum[blockIdx.x] = wsums[0] + wsums[1] + wsums[2] + wsums[3];
}

// ---------------------------------------------------------------------------
// scan3b: rowptr from counts; wave 0 re-scans the <=64 chunk sums locally
// (absorbs old scan2 kernel).
// ---------------------------------------------------------------------------
__global__ __launch_bounds__(256) void scan3b_kernel(const int* __restrict__ counts,
                                                     const int* __restrict__ csum,
                                                     int* __restrict__ rowptr,
                                                     int N, int E, int nchunk) {
    __shared__ int wsums[4];
    __shared__ int coff_s;
    const int tid = threadIdx.x, lane = tid & 63, wv = tid >> 6;
    if (tid < 64) {
        int v = (tid < nchunk) ? csum[tid] : 0;
        int incl = v;
#pragma unroll
        for (int off = 1; off < 64; off <<= 1) {
            int t = __shfl_up(incl, off);
            if (tid >= off) incl += t;
        }
        if (tid == blockIdx.x) coff_s = incl - v;
        if (blockIdx.x == 0 && tid == 0) rowptr[N] = E;
    }
    int i0 = blockIdx.x * 1024 + tid * 4;
    int v0 = 0, v1 = 0, v2 = 0, v3 = 0;
    if (i0 + 3 < N) {
        int4 v = *(const int4*)(counts + i0);
        v0 = v.x; v1 = v.y; v2 = v.z; v3 = v.w;
    } else {
        if (i0 + 0 < N) v0 = counts[i0 + 0];
        if (i0 + 1 < N) v1 = counts[i0 + 1];
        if (i0 + 2 < N) v2 = counts[i0 + 2];
        if (i0 + 3 < N) v3 = counts[i0 + 3];
    }
    int tt = v0 + v1 + v2 + v3;
    int incl = tt;
#pragma unroll
    for (int off = 1; off < 64; off <<= 1) {
        int t = __shfl_up(incl, off);
        if (lane >= off) incl += t;
    }
    if (lane == 63) wsums[wv] = incl;
    __syncthreads();
    int woff = 0;
    for (int w2 = 0; w2 < wv; ++w2) woff += wsums[w2];
    int base = coff_s + woff + (incl - tt);
    if (i0 + 0 < N) rowptr[i0 + 0] = base;
    if (i0 + 1 < N) rowptr[i0 + 1] = base + v0;
    if (i0 + 2 < N) rowptr[i0 + 2] = base + v0 + v1;
    if (i0 + 3 < N) rowptr[i0 + 3] = base + v0 + v1 + v2;
}

// ---------------------------------------------------------------------------
// scatter: pos = rowptr[dst] + eslot[e]; write {ex0,ex1,ex2,src}. No atomics.
// Max-shift skipped: softmax shift-invariant, scores bounded, eps negligible.
// ---------------------------------------------------------------------------
__global__ __launch_bounds__(256) void scatter_kernel(const int* __restrict__ ei,
                                                      const float* __restrict__ ef,
                                                      const float* __restrict__ s1,
                                                      const float* __restrict__ s2,
                                                      const int* __restrict__ rowptr,
                                                      const int* __restrict__ eslot,
                                                      float4* __restrict__ rec, int E) {
    int e = blockIdx.x * blockDim.x + threadIdx.x;
    if (e >= E) return;
    int src = ei[e];
    int dst = ei[E + e];
    float s = s1[src] + s2[dst];
    s = (s >= 0.f) ? s : ALPHA * s;
    float ex0 = __expf(s * ef[e * 3 + 0]);
    float ex1 = __expf(s * ef[e * 3 + 1]);
    float ex2 = __expf(s * ef[e * 3 + 2]);
    int pos = rowptr[dst] + eslot[e];
    rec[pos] = make_float4(ex0, ex1, ex2, __int_as_float(src));
}

// ---------------------------------------------------------------------------
// agg: one wave per node, atomic-free. Lane-parallel denominator pass +
// xor-butterfly. Main: x8-unrolled gather of bf16 Y rows (768B/edge, 24
// loads in flight), fp32 accumulate, one float2 store per lane.
// ---------------------------------------------------------------------------
__global__ __launch_bounds__(256) void agg_kernel(const float4* __restrict__ rec,
                                                  const int* __restrict__ rowptr,
                                                  const uint32* __restrict__ Yu,
                                                  float* __restrict__ out, int N) {
    int node = (blockIdx.x * blockDim.x + threadIdx.x) >> 6;
    int lane = threadIdx.x & 63;
    if (node >= N) return;
    int beg = rowptr[node], end = rowptr[node + 1];

    float d0 = 0.f, d1 = 0.f, d2 = 0.f;
    for (int jb = beg + lane; jb < end; jb += 64) {
        float4 r = rec[jb];
        d0 += r.x; d1 += r.y; d2 += r.z;
    }
#pragma unroll
    for (int off = 32; off > 0; off >>= 1) {
        d0 += __shfl_xor(d0, off);
        d1 += __shfl_xor(d1, off);
        d2 += __shfl_xor(d2, off);
    }
    float inv0 = 1.f / (d0 + 1e-16f);
    float inv1 = 1.f / (d1 + 1e-16f);
    float inv2 = 1.f / (d2 + 1e-16f);

    float a0 = 0.f, a1 = 0.f;
    int j = beg;
    for (; j + 7 < end; j += 8) {
        float4 r[8]; const uint32* p[8]; uint32 u[8][3];
#pragma unroll
        for (int t = 0; t < 8; ++t) {
            r[t] = rec[j + t];
            p[t] = Yu + (size_t)__float_as_int(r[t].w) * 192;
        }
#pragma unroll
        for (int t = 0; t < 8; ++t) {
            u[t][0] = p[t][lane]; u[t][1] = p[t][64 + lane]; u[t][2] = p[t][128 + lane];
        }
#pragma unroll
        for (int t = 0; t < 8; ++t) {
            float w0 = r[t].x * inv0, w1 = r[t].y * inv1, w2 = r[t].z * inv2;
            a0 += w0 * bflo(u[t][0]) + w1 * bflo(u[t][1]) + w2 * bflo(u[t][2]);
            a1 += w0 * bfhi(u[t][0]) + w1 * bfhi(u[t][1]) + w2 * bfhi(u[t][2]);
        }
    }
    for (; j + 1 < end; j += 2) {
        float4 r0 = rec[j], r1 = rec[j + 1];
        const uint32* p0 = Yu + (size_t)__float_as_int(r0.w) * 192;
        const uint32* p1 = Yu + (size_t)__float_as_int(r1.w) * 192;
        uint32 u00 = p0[lane], u01 = p0[64 + lane], u02 = p0[128 + lane];
        uint32 u10 = p1[lane], u11 = p1[64 + lane], u12 = p1[128 + lane];
        float w00 = r0.x * inv0, w01 = r0.y * inv1, w02 = r0.z * inv2;
        float w10 = r1.x * inv0, w11 = r1.y * inv1, w12 = r1.z * inv2;
        a0 += w00 * bflo(u00) + w01 * bflo(u01) + w02 * bflo(u02);
        a1 += w00 * bfhi(u00) + w01 * bfhi(u01) + w02 * bfhi(u02);
        a0 += w10 * bflo(u10) + w11 * bflo(u11) + w12 * bflo(u12);
        a1 += w10 * bfhi(u10) + w11 * bfhi(u11) + w12 * bfhi(u12);
    }
    if (j < end) {
        float4 r0 = rec[j];
        const uint32* p0 = Yu + (size_t)__float_as_int(r0.w) * 192;
        uint32 u00 = p0[lane], u01 = p0[64 + lane], u02 = p0[128 + lane];
        float w00 = r0.x * inv0, w01 = r0.y * inv1, w02 = r0.z * inv2;
        a0 += w00 * bflo(u00) + w01 * bflo(u01) + w02 * bflo(u02);
        a1 += w00 * bfhi(u00) + w01 * bfhi(u01) + w02 * bfhi(u02);
    }
    ((float2*)(out + (size_t)node * 128))[lane] = make_float2(a0, a1);
}

// ---------------------------------------------------------------------------
extern "C" void kernel_launch(void* const* d_in, const int* in_sizes, int n_in,
                              void* d_out, int out_size, void* d_ws, size_t ws_size,
                              hipStream_t stream) {
    const float* h    = (const float*)d_in[0];
    const int*   ei   = (const int*)d_in[1];    // [2, E]
    const float* ef   = (const float*)d_in[2];  // [E, 3]
    const float* W    = (const float*)d_in[3];  // [128,128]
    const float* a1   = (const float*)d_in[4];  // [128]
    const float* a2   = (const float*)d_in[5];  // [128]
    const float* Wout = (const float*)d_in[6];  // [384,128]
    float*       out  = (float*)d_out;

    const int N = in_sizes[0] / 128;  // 50000
    const int E = in_sizes[2] / 3;    // 800000
    const int nchunk = (N + 1023) / 1024;

    // workspace layout (rec first -> 16B alignment for everything vectorized)
    float4* rec = (float4*)d_ws;                        // E * 16B
    unsigned short* Yb  = (unsigned short*)(rec + E);   // N*384 bf16
    unsigned short* WT2 = Yb + (size_t)N * 384;         // 3*128*128 bf16
    float* w1f  = (float*)(WT2 + 3 * 128 * 128);        // 128
    float* w2f  = w1f + 128;                            // 128
    float* s1   = w2f + 128;                            // N
    float* s2   = s1 + N;                               // N
    int* counts = (int*)(s2 + N);                       // N
    int* rowptr = counts + N;                           // N+1
    int* eslot  = rowptr + N + 1;                       // E
    int* csum   = eslot + E;                            // nchunk (<=64)

    hipMemsetAsync(counts, 0, (size_t)N * sizeof(int), stream);

    hist_kernel<<<(E + 255) / 256, 256, 0, stream>>>(ei, counts, eslot, E);
    prep2_kernel<<<25, 256, 0, stream>>>(W, Wout, a1, a2, WT2, w1f, w2f);
    mmy2_kernel<<<(N + 127) / 128, 256, 0, stream>>>(h, WT2, w1f, w2f, Yb, s1, s2, N);
    scan1_kernel<<<nchunk, 256, 0, stream>>>(counts, csum, N);
    scan3b_kernel<<<nchunk, 256, 0, stream>>>(counts, csum, rowptr, N, E, nchunk);
    scatter_kernel<<<(E + 255) / 256, 256, 0, stream>>>(ei, ef, s1, s2, rowptr, eslot, rec, E);
    agg_kernel<<<(N * 64 + 255) / 256, 256, 0, stream>>>(rec, rowptr, (const uint32*)Yb, out, N);
}